// Round 3
// baseline (601.715 us; speedup 1.0000x reference)
//
#include <hip/hip_runtime.h>
#include <hip/hip_cooperative_groups.h>
#include <hip/hip_bf16.h>

namespace cg = cooperative_groups;

typedef __hip_bfloat16 bf16;
typedef __bf16 bf16x8v __attribute__((ext_vector_type(8)));
typedef float f32x4 __attribute__((ext_vector_type(4)));
typedef unsigned short u16x8 __attribute__((ext_vector_type(8)));

#define CAP 128  // fixed per-node CSR capacity (mean deg 33; P(deg>128) ~ 0)

__device__ __forceinline__ float bits2f(unsigned short u) {
  union { unsigned int i; float f; } c;
  c.i = ((unsigned int)u) << 16;
  return c.f;
}

// ---------------- shared MFMA GEMM body (r10-verified, BK=128) ----------------
// H[64 rows @ m0, 64 cols @ head hd] = X @ Wt^T + fused attention dots.

template <bool FP32IN>
__device__ __forceinline__ void gemm_body(const void* __restrict__ Xv,
                                          const bf16* __restrict__ Wt,
                                          const float* __restrict__ att_s,
                                          const float* __restrict__ att_d,
                                          bf16* __restrict__ H, float* __restrict__ a_s,
                                          float* __restrict__ a_d, int M, int m0, int hd,
                                          bf16* As, bf16* Bs) {
  const int LDK = 136;
  int tid = threadIdx.x;
  int wave = tid >> 6, lane = tid & 63;
  int quad = lane >> 4, l16 = lane & 15;
  int n0 = hd * 64;
  int srow = tid >> 2;
  int koff = (tid & 3) * 32;

  const float* Xf = (const float*)Xv;
  const bf16*  Xb = (const bf16*)Xv;

  f32x4 acc[4] = {{0.f, 0.f, 0.f, 0.f}, {0.f, 0.f, 0.f, 0.f},
                  {0.f, 0.f, 0.f, 0.f}, {0.f, 0.f, 0.f, 0.f}};

  for (int ks = 0; ks < 256; ks += 128) {
    int gm = m0 + srow;
#pragma unroll
    for (int c = 0; c < 4; c++) {
      int ko = koff + c * 8;
      uint4 v;
      if (FP32IN) {
        float4 u0 = make_float4(0.f, 0.f, 0.f, 0.f), u1 = u0;
        if (gm < M) {
          u0 = *(const float4*)&Xf[gm * 256 + ks + ko];
          u1 = *(const float4*)&Xf[gm * 256 + ks + ko + 4];
        }
        union { bf16 h[8]; uint4 u; } pk;
        pk.h[0] = __float2bfloat16(u0.x); pk.h[1] = __float2bfloat16(u0.y);
        pk.h[2] = __float2bfloat16(u0.z); pk.h[3] = __float2bfloat16(u0.w);
        pk.h[4] = __float2bfloat16(u1.x); pk.h[5] = __float2bfloat16(u1.y);
        pk.h[6] = __float2bfloat16(u1.z); pk.h[7] = __float2bfloat16(u1.w);
        v = pk.u;
      } else {
        v = (gm < M) ? *(const uint4*)&Xb[gm * 256 + ks + ko]
                     : make_uint4(0u, 0u, 0u, 0u);
      }
      *(uint4*)&As[srow * LDK + ko] = v;
    }
#pragma unroll
    for (int c = 0; c < 4; c++) {
      int ko = koff + c * 8;
      *(uint4*)&Bs[srow * LDK + ko] = *(const uint4*)&Wt[(n0 + srow) * 256 + ks + ko];
    }
    __syncthreads();

#pragma unroll
    for (int kk = 0; kk < 4; kk++) {
      bf16x8v af = *(const bf16x8v*)&As[(wave * 16 + l16) * LDK + kk * 32 + quad * 8];
#pragma unroll
      for (int t = 0; t < 4; t++) {
        bf16x8v bfr = *(const bf16x8v*)&Bs[(t * 16 + l16) * LDK + kk * 32 + quad * 8];
        acc[t] = __builtin_amdgcn_mfma_f32_16x16x32_bf16(af, bfr, acc[t], 0, 0, 0);
      }
    }
    __syncthreads();
  }

  float ps[4] = {0.f, 0.f, 0.f, 0.f}, pd[4] = {0.f, 0.f, 0.f, 0.f};
#pragma unroll
  for (int t = 0; t < 4; t++) {
    float sa = att_s[hd * 64 + t * 16 + l16];
    float da = att_d[hd * 64 + t * 16 + l16];
#pragma unroll
    for (int j = 0; j < 4; j++) {
      int gm = m0 + wave * 16 + quad * 4 + j;
      float v = acc[t][j];
      if (gm < M) H[gm * 256 + n0 + t * 16 + l16] = __float2bfloat16(v);
      ps[j] += v * sa;
      pd[j] += v * da;
    }
  }
#pragma unroll
  for (int j = 0; j < 4; j++) {
#pragma unroll
    for (int s = 1; s < 16; s <<= 1) {
      ps[j] += __shfl_xor(ps[j], s, 64);
      pd[j] += __shfl_xor(pd[j], s, 64);
    }
    int gm = m0 + wave * 16 + quad * 4 + j;
    if (l16 == 0 && gm < M) {
      a_s[gm * 4 + hd] = ps[j];
      a_d[gm * 4 + hd] = pd[j];
    }
  }
}

// ---------------- wave-per-node agg stage (device fn, grid-stride) ----------------

__device__ __forceinline__ void agg_stage(const bf16* __restrict__ H,
                                          const float* __restrict__ a_s,
                                          const float* __restrict__ a_d,
                                          const int* __restrict__ cnt,
                                          const int* __restrict__ csr,
                                          const float* __restrict__ bias,
                                          bf16* __restrict__ OutB,
                                          float* __restrict__ OutF, int N,
                                          bool final_, char* smem, int blk, int nblk) {
  int tid = threadIdx.x;
  int wave = tid >> 6, lane = tid & 63;
  int* wIdx = (int*)smem + wave * 128;                 // 4*128*4 = 2048 B
  float* wP = (float*)(smem + 2048) + wave * 512;      // 4*512*4 = 8192 B
  int ngr = (N + 3) >> 2;
  for (int ng = blk; ng < ngr; ng += nblk) {
    int n = ng * 4 + wave;
    int deg = 0, degp = 0;
    if (n < N) {
      deg = min(cnt[n], CAP);
      degp = (deg + 7) & ~7;          // pad to multiple of 8 edges
      float4 ad4 = *(const float4*)&a_d[n * 4];
#pragma unroll
      for (int base = 0; base < 2; base++) {
        int jj = base * 64 + lane;
        if (jj < deg) {
          int src = csr[n * CAP + jj];
          wIdx[jj] = src;
          float4 as4 = *(const float4*)&a_s[src * 4];
          float4 e;
          e.x = as4.x + ad4.x; e.x = (e.x > 0.f) ? e.x : 0.2f * e.x;
          e.y = as4.y + ad4.y; e.y = (e.y > 0.f) ? e.y : 0.2f * e.y;
          e.z = as4.z + ad4.z; e.z = (e.z > 0.f) ? e.z : 0.2f * e.z;
          e.w = as4.w + ad4.w; e.w = (e.w > 0.f) ? e.w : 0.2f * e.w;
          float4 pv;
          pv.x = __expf(e.x); pv.y = __expf(e.y);
          pv.z = __expf(e.z); pv.w = __expf(e.w);
          *(float4*)&wP[jj * 4] = pv;
        }
      }
      int pad = degp - deg;           // 0..7
      if (lane < pad) {
        wIdx[deg + lane] = 0;
        *(float4*)&wP[(deg + lane) * 4] = make_float4(0.f, 0.f, 0.f, 0.f);
      }
    }
    __syncthreads();
    if (n < N) {
      int sel = lane >> 5;            // 0: even edges, 1: odd edges
      int l32 = lane & 31;
      int c8 = l32 * 8;               // 8 channels per lane
      int head = l32 >> 3;
      const unsigned short* Hs = (const unsigned short*)H;

      float acc[8] = {0.f, 0.f, 0.f, 0.f, 0.f, 0.f, 0.f, 0.f};
      float s = 0.f;
      int npairp = degp >> 1;         // multiple of 4

      for (int it = 0; it < npairp; it += 4) {
        int jv[4]; int sv[4]; float pv[4]; u16x8 hv[4];
#pragma unroll
        for (int u = 0; u < 4; u++) jv[u] = 2 * (it + u) + sel;
#pragma unroll
        for (int u = 0; u < 4; u++) sv[u] = wIdx[jv[u]];
#pragma unroll
        for (int u = 0; u < 4; u++) pv[u] = wP[jv[u] * 4 + head];
#pragma unroll
        for (int u = 0; u < 4; u++) hv[u] = *(const u16x8*)(Hs + sv[u] * 256 + c8);
#pragma unroll
        for (int u = 0; u < 4; u++) {
          s += pv[u];
#pragma unroll
          for (int k = 0; k < 8; k++) acc[k] += pv[u] * bits2f(hv[u][k]);
        }
      }

      s += __shfl_xor(s, 32, 64);
#pragma unroll
      for (int k = 0; k < 8; k++) acc[k] += __shfl_xor(acc[k], 32, 64);

      if (sel == 0) {
        float inv = 1.f / (s + 1e-16f);
        float4 b0 = *(const float4*)&bias[c8];
        float4 b1 = *(const float4*)&bias[c8 + 4];
        float v[8];
        v[0] = acc[0] * inv + b0.x; v[1] = acc[1] * inv + b0.y;
        v[2] = acc[2] * inv + b0.z; v[3] = acc[3] * inv + b0.w;
        v[4] = acc[4] * inv + b1.x; v[5] = acc[5] * inv + b1.y;
        v[6] = acc[6] * inv + b1.z; v[7] = acc[7] * inv + b1.w;
#pragma unroll
        for (int k = 0; k < 8; k++) v[k] = (v[k] > 0.f) ? v[k] : expm1f(v[k]);
        if (final_) {
          *(float4*)&OutF[n * 256 + c8]     = make_float4(v[0], v[1], v[2], v[3]);
          *(float4*)&OutF[n * 256 + c8 + 4] = make_float4(v[4], v[5], v[6], v[7]);
        } else {
          union { bf16 h[8]; u16x8 u; } pk;
#pragma unroll
          for (int k = 0; k < 8; k++) pk.h[k] = __float2bfloat16(v[k]);
          *(u16x8*)((unsigned short*)OutB + n * 256 + c8) = pk.u;
        }
      }
    }
  }
}

// ---------------- uber: whole 3-layer GAT in one cooperative dispatch ----------------
// Stage LDS union: gemm As+Bs (34816 B) >= agg wIdx+wP (10240 B) >= wt tile (1088 B).

__global__ void __launch_bounds__(256, 4)
uber_kernel(const float* __restrict__ x, const int* __restrict__ ei,
            const float* __restrict__ W0, const float* __restrict__ as0,
            const float* __restrict__ ad0, const float* __restrict__ bias0,
            const float* __restrict__ W1, const float* __restrict__ as1,
            const float* __restrict__ ad1, const float* __restrict__ bias1,
            const float* __restrict__ W2, const float* __restrict__ as2,
            const float* __restrict__ ad2, const float* __restrict__ bias2,
            int* __restrict__ cnt, int* __restrict__ csr,
            float* __restrict__ a_s, float* __restrict__ a_d,
            bf16* __restrict__ Wt, bf16* __restrict__ h_buf,
            bf16* __restrict__ x_buf, float* __restrict__ outp, int N, int E) {
  cg::grid_group grid = cg::this_grid();
  __shared__ char smem[34816];
  bf16* As = (bf16*)smem;
  bf16* Bs = (bf16*)smem + 64 * 136;
  int nblk = (int)gridDim.x;
  int blk = (int)blockIdx.x;
  int tid = threadIdx.x;

  // ---- S1: weight transpose + cnt zero ----
  {
    float(*tile)[17] = (float(*)[17])smem;
    int zb = (N + 255) >> 8;
    for (int b = blk; b < 768 + zb; b += nblk) {
      if (b < 768) {
        int L = b >> 8, rem = b & 255;
        const float* W = (L == 0) ? W0 : (L == 1) ? W1 : W2;
        bf16* T = Wt + (size_t)L * 65536;
        int n0 = (rem & 15) * 16, k0 = (rem >> 4) * 16;
        int tx = tid & 15, ty = tid >> 4;
        tile[ty][tx] = W[(k0 + ty) * 256 + n0 + tx];
        __syncthreads();
        T[(n0 + ty) * 256 + k0 + tx] = __float2bfloat16(tile[tx][ty]);
      } else {
        int idx = (b - 768) * 256 + tid;
        if (idx < N) cnt[idx] = 0;
      }
      __syncthreads();
    }
  }
  grid.sync();

  // ---- S2: layer-1 GEMM (fp32 in) + CSR fill ----
  int ngb = ((N + 63) >> 6) * 4;
  for (int j = blk; j < ngb; j += nblk)
    gemm_body<true>(x, Wt, as0, ad0, h_buf, a_s, a_d, N, (j >> 2) * 64, j & 3, As, Bs);
  int eb = (E + N + 255) >> 8;
  for (int j = blk; j < eb; j += nblk) {
    int t = j * 256 + tid;
    if (t < E + N) {
      int s_, d_;
      if (t < E) { s_ = ei[t]; d_ = ei[E + t]; }
      else       { s_ = t - E; d_ = t - E; }
      int pos = atomicAdd(&cnt[d_], 1);
      if (pos < CAP) csr[d_ * CAP + pos] = s_;
    }
  }
  grid.sync();

  // ---- S3: agg layer 1 ----
  agg_stage(h_buf, a_s, a_d, cnt, csr, bias0, x_buf, nullptr, N, false, smem, blk, nblk);
  grid.sync();

  // ---- S4: layer-2 GEMM ----
  for (int j = blk; j < ngb; j += nblk)
    gemm_body<false>(x_buf, Wt + 65536, as1, ad1, h_buf, a_s, a_d, N, (j >> 2) * 64,
                     j & 3, As, Bs);
  grid.sync();

  // ---- S5: agg layer 2 ----
  agg_stage(h_buf, a_s, a_d, cnt, csr, bias1, x_buf, nullptr, N, false, smem, blk, nblk);
  grid.sync();

  // ---- S6: layer-3 GEMM ----
  for (int j = blk; j < ngb; j += nblk)
    gemm_body<false>(x_buf, Wt + 131072, as2, ad2, h_buf, a_s, a_d, N, (j >> 2) * 64,
                     j & 3, As, Bs);
  grid.sync();

  // ---- S7: agg layer 3 (final, fp32 out) ----
  agg_stage(h_buf, a_s, a_d, cnt, csr, bias2, nullptr, outp, N, true, smem, blk, nblk);
}

// ---------------- legacy kernels (fallback path, proven @189us) ----------------

__global__ void wt_zero_kernel(const float* __restrict__ W0, const float* __restrict__ W1,
                               const float* __restrict__ W2, bf16* __restrict__ Wt,
                               int* __restrict__ cnt, int N) {
  __shared__ float tile[16][17];
  int b = blockIdx.x;
  if (b < 768) {
    int L = b >> 8, rem = b & 255;
    const float* W = (L == 0) ? W0 : (L == 1) ? W1 : W2;
    bf16* T = Wt + (size_t)L * 65536;
    int n0 = (rem & 15) * 16, k0 = (rem >> 4) * 16;
    int tx = threadIdx.x & 15, ty = threadIdx.x >> 4;
    tile[ty][tx] = W[(k0 + ty) * 256 + n0 + tx];
    __syncthreads();
    T[(n0 + ty) * 256 + k0 + tx] = __float2bfloat16(tile[tx][ty]);
  } else {
    int idx = (b - 768) * 256 + threadIdx.x;
    if (idx < N) cnt[idx] = 0;
  }
}

__global__ void __launch_bounds__(256, 4)
gemm_mfma_kernel(const bf16* __restrict__ X, const bf16* __restrict__ Wt,
                 const float* __restrict__ att_s, const float* __restrict__ att_d,
                 bf16* __restrict__ H, float* __restrict__ a_s, float* __restrict__ a_d,
                 int M) {
  __shared__ bf16 As[64 * 136];
  __shared__ bf16 Bs[64 * 136];
  gemm_body<false>(X, Wt, att_s, att_d, H, a_s, a_d, M, blockIdx.x * 64, blockIdx.y,
                   As, Bs);
}

__global__ void __launch_bounds__(256, 4)
gemm1_fill_kernel(const float* __restrict__ X, const bf16* __restrict__ Wt,
                  const float* __restrict__ att_s, const float* __restrict__ att_d,
                  bf16* __restrict__ H, float* __restrict__ a_s, float* __restrict__ a_d,
                  int M, const int* __restrict__ ei, int E, int N,
                  int* __restrict__ cnt, int* __restrict__ csr, int ngb) {
  __shared__ bf16 As[64 * 136];
  __shared__ bf16 Bs[64 * 136];
  int b = blockIdx.x;
  if (b < ngb) {
    gemm_body<true>(X, Wt, att_s, att_d, H, a_s, a_d, M, (b >> 2) * 64, b & 3, As, Bs);
  } else {
    int t = (b - ngb) * 256 + threadIdx.x;
    if (t >= E + N) return;
    int src, dst;
    if (t < E) { src = ei[t]; dst = ei[E + t]; }
    else       { src = t - E; dst = t - E; }
    int pos = atomicAdd(&cnt[dst], 1);
    if (pos < CAP) csr[dst * CAP + pos] = src;
  }
}

template <bool FINAL>
__global__ void __launch_bounds__(256, 8)
agg_wave_kernel(const bf16* __restrict__ H, const float* __restrict__ a_s,
                const float* __restrict__ a_d, const int* __restrict__ cnt,
                const int* __restrict__ csr, const float* __restrict__ bias,
                bf16* __restrict__ OutB, float* __restrict__ OutF, int N) {
  __shared__ char smem[10240];
  agg_stage(H, a_s, a_d, cnt, csr, bias, OutB, OutF, N, FINAL, smem, blockIdx.x,
            gridDim.x);
}

// ---------------- launch ----------------

extern "C" void kernel_launch(void* const* d_in, const int* in_sizes, int n_in,
                              void* d_out, int out_size, void* d_ws, size_t ws_size,
                              hipStream_t stream) {
  const int N = in_sizes[0] / 256;   // 10000
  const int E = in_sizes[1] / 2;     // 320000

  const float* x  = (const float*)d_in[0];
  const int*   ei = (const int*)d_in[1];
  const float* W0 = (const float*)d_in[2];
  const float* as0 = (const float*)d_in[3];
  const float* ad0 = (const float*)d_in[4];
  const float* bz0 = (const float*)d_in[5];
  const float* W1 = (const float*)d_in[6];
  const float* as1 = (const float*)d_in[7];
  const float* ad1 = (const float*)d_in[8];
  const float* bz1 = (const float*)d_in[9];
  const float* W2 = (const float*)d_in[10];
  const float* as2 = (const float*)d_in[11];
  const float* ad2 = (const float*)d_in[12];
  const float* bz2 = (const float*)d_in[13];
  float* out = (float*)d_out;

  char* p = (char*)d_ws;
  auto carve = [&](size_t bytes) {
    char* r = p;
    p += (bytes + 255) & ~size_t(255);
    return r;
  };
  int*   cnt   = (int*)carve(sizeof(int) * N);
  int*   csr   = (int*)carve(sizeof(int) * N * CAP);
  float* a_s   = (float*)carve(sizeof(float) * N * 4);
  float* a_d   = (float*)carve(sizeof(float) * N * 4);
  bf16*  Wt    = (bf16*)carve(sizeof(bf16) * 3 * 65536);
  bf16*  h_buf = (bf16*)carve(sizeof(bf16) * N * 256);
  bf16*  x_buf = (bf16*)carve(sizeof(bf16) * N * 256);
  (void)ws_size; (void)n_in; (void)out_size;

  // cooperative uber launch, occupancy-clamped
  int nb = 0;
  if (hipOccupancyMaxActiveBlocksPerMultiprocessor(&nb, uber_kernel, 256, 0) !=
          hipSuccess || nb < 1)
    nb = 4;
  if (nb > 4) nb = 4;
  int devCU = 0, dev = 0;
  hipGetDevice(&dev);
  if (hipDeviceGetAttribute(&devCU, hipDeviceAttributeMultiprocessorCount, dev) !=
          hipSuccess || devCU <= 0)
    devCU = 256;
  int gridX = devCU * nb;

  int Ni = N, Ei = E;
  void* args[] = {(void*)&x,   (void*)&ei,  (void*)&W0,  (void*)&as0, (void*)&ad0,
                  (void*)&bz0, (void*)&W1,  (void*)&as1, (void*)&ad1, (void*)&bz1,
                  (void*)&W2,  (void*)&as2, (void*)&ad2, (void*)&bz2, (void*)&cnt,
                  (void*)&csr, (void*)&a_s, (void*)&a_d, (void*)&Wt,  (void*)&h_buf,
                  (void*)&x_buf, (void*)&out, (void*)&Ni, (void*)&Ei};
  hipError_t cerr = hipLaunchCooperativeKernel((const void*)uber_kernel, dim3(gridX),
                                               dim3(256), args, 0, stream);
  if (cerr == hipSuccess) return;

  // ---- fallback: proven 7-dispatch path ----
  const int zb = (N + 255) / 256;
  const int eb = (E + N + 255) / 256;
  const int ngb = ((N + 63) / 64) * 4;
  const int ab = (N + 3) / 4;
  dim3 ggrid((N + 63) / 64, 4);

  wt_zero_kernel<<<768 + zb, 256, 0, stream>>>(W0, W1, W2, Wt, cnt, N);
  gemm1_fill_kernel<<<ngb + eb, 256, 0, stream>>>(x, Wt, as0, ad0, h_buf, a_s, a_d, N,
                                                  ei, E, N, cnt, csr, ngb);
  agg_wave_kernel<false><<<ab, 256, 0, stream>>>(h_buf, a_s, a_d, cnt, csr, bz0, x_buf,
                                                 nullptr, N);
  gemm_mfma_kernel<<<ggrid, 256, 0, stream>>>(x_buf, Wt + 65536, as1, ad1, h_buf, a_s,
                                              a_d, N);
  agg_wave_kernel<false><<<ab, 256, 0, stream>>>(h_buf, a_s, a_d, cnt, csr, bz1, x_buf,
                                                 nullptr, N);
  gemm_mfma_kernel<<<ggrid, 256, 0, stream>>>(x_buf, Wt + 131072, as2, ad2, h_buf, a_s,
                                              a_d, N);
  agg_wave_kernel<true><<<ab, 256, 0, stream>>>(h_buf, a_s, a_d, cnt, csr, bz2, nullptr,
                                                out, N);
}

// Round 4
// 288.685 us; speedup vs baseline: 2.0843x; 2.0843x over previous
//
#include <hip/hip_runtime.h>
#include <hip/hip_bf16.h>

typedef __hip_bfloat16 bf16;
typedef __bf16 bf16x8v __attribute__((ext_vector_type(8)));
typedef float f32x4 __attribute__((ext_vector_type(4)));
typedef unsigned short u16x8 __attribute__((ext_vector_type(8)));

#define CAP 128  // fixed per-node CSR capacity (mean deg 33; P(deg>128) ~ 0)

__device__ __forceinline__ float bits2f(unsigned short u) {
  union { unsigned int i; float f; } c;
  c.i = ((unsigned int)u) << 16;
  return c.f;
}

// ---------------- wt transpose + cnt zero (one dispatch) ----------------

__global__ void wt_zero_kernel(const float* __restrict__ W0, const float* __restrict__ W1,
                               const float* __restrict__ W2, bf16* __restrict__ Wt,
                               int* __restrict__ cnt, int N) {
  __shared__ float tile[16][17];
  int b = blockIdx.x;
  if (b < 768) {
    int L = b >> 8, rem = b & 255;
    const float* W = (L == 0) ? W0 : (L == 1) ? W1 : W2;
    bf16* T = Wt + (size_t)L * 65536;
    int n0 = (rem & 15) * 16, k0 = (rem >> 4) * 16;
    int tx = threadIdx.x & 15, ty = threadIdx.x >> 4;
    tile[ty][tx] = W[(k0 + ty) * 256 + n0 + tx];
    __syncthreads();
    T[(n0 + ty) * 256 + k0 + tx] = __float2bfloat16(tile[tx][ty]);
  } else {
    int idx = (b - 768) * 256 + threadIdx.x;
    if (idx < N) cnt[idx] = 0;
  }
}

// ---------------- shared MFMA GEMM body (r10-verified, BK=128) ----------------

template <bool FP32IN>
__device__ __forceinline__ void gemm_body(const void* __restrict__ Xv,
                                          const bf16* __restrict__ Wt,
                                          const float* __restrict__ att_s,
                                          const float* __restrict__ att_d,
                                          bf16* __restrict__ H, float* __restrict__ a_s,
                                          float* __restrict__ a_d, int M, int m0, int hd,
                                          bf16* As, bf16* Bs) {
  const int LDK = 136;
  int tid = threadIdx.x;
  int wave = tid >> 6, lane = tid & 63;
  int quad = lane >> 4, l16 = lane & 15;
  int n0 = hd * 64;
  int srow = tid >> 2;
  int koff = (tid & 3) * 32;

  const float* Xf = (const float*)Xv;
  const bf16*  Xb = (const bf16*)Xv;

  f32x4 acc[4] = {{0.f, 0.f, 0.f, 0.f}, {0.f, 0.f, 0.f, 0.f},
                  {0.f, 0.f, 0.f, 0.f}, {0.f, 0.f, 0.f, 0.f}};

  for (int ks = 0; ks < 256; ks += 128) {
    int gm = m0 + srow;
#pragma unroll
    for (int c = 0; c < 4; c++) {
      int ko = koff + c * 8;
      uint4 v;
      if (FP32IN) {
        float4 u0 = make_float4(0.f, 0.f, 0.f, 0.f), u1 = u0;
        if (gm < M) {
          u0 = *(const float4*)&Xf[gm * 256 + ks + ko];
          u1 = *(const float4*)&Xf[gm * 256 + ks + ko + 4];
        }
        union { bf16 h[8]; uint4 u; } pk;
        pk.h[0] = __float2bfloat16(u0.x); pk.h[1] = __float2bfloat16(u0.y);
        pk.h[2] = __float2bfloat16(u0.z); pk.h[3] = __float2bfloat16(u0.w);
        pk.h[4] = __float2bfloat16(u1.x); pk.h[5] = __float2bfloat16(u1.y);
        pk.h[6] = __float2bfloat16(u1.z); pk.h[7] = __float2bfloat16(u1.w);
        v = pk.u;
      } else {
        v = (gm < M) ? *(const uint4*)&Xb[gm * 256 + ks + ko]
                     : make_uint4(0u, 0u, 0u, 0u);
      }
      *(uint4*)&As[srow * LDK + ko] = v;
    }
#pragma unroll
    for (int c = 0; c < 4; c++) {
      int ko = koff + c * 8;
      *(uint4*)&Bs[srow * LDK + ko] = *(const uint4*)&Wt[(n0 + srow) * 256 + ks + ko];
    }
    __syncthreads();

#pragma unroll
    for (int kk = 0; kk < 4; kk++) {
      bf16x8v af = *(const bf16x8v*)&As[(wave * 16 + l16) * LDK + kk * 32 + quad * 8];
#pragma unroll
      for (int t = 0; t < 4; t++) {
        bf16x8v bfr = *(const bf16x8v*)&Bs[(t * 16 + l16) * LDK + kk * 32 + quad * 8];
        acc[t] = __builtin_amdgcn_mfma_f32_16x16x32_bf16(af, bfr, acc[t], 0, 0, 0);
      }
    }
    __syncthreads();
  }

  float ps[4] = {0.f, 0.f, 0.f, 0.f}, pd[4] = {0.f, 0.f, 0.f, 0.f};
#pragma unroll
  for (int t = 0; t < 4; t++) {
    float sa = att_s[hd * 64 + t * 16 + l16];
    float da = att_d[hd * 64 + t * 16 + l16];
#pragma unroll
    for (int j = 0; j < 4; j++) {
      int gm = m0 + wave * 16 + quad * 4 + j;
      float v = acc[t][j];
      if (gm < M) H[gm * 256 + n0 + t * 16 + l16] = __float2bfloat16(v);
      ps[j] += v * sa;
      pd[j] += v * da;
    }
  }
#pragma unroll
  for (int j = 0; j < 4; j++) {
#pragma unroll
    for (int s = 1; s < 16; s <<= 1) {
      ps[j] += __shfl_xor(ps[j], s, 64);
      pd[j] += __shfl_xor(pd[j], s, 64);
    }
    int gm = m0 + wave * 16 + quad * 4 + j;
    if (l16 == 0 && gm < M) {
      a_s[gm * 4 + hd] = ps[j];
      a_d[gm * 4 + hd] = pd[j];
    }
  }
}

// layer 1 merged with CSR fill: blocks [0,ngb) gemm, [ngb,...) scatter edges.
__global__ void __launch_bounds__(256, 4)
gemm1_fill_kernel(const float* __restrict__ X, const bf16* __restrict__ Wt,
                  const float* __restrict__ att_s, const float* __restrict__ att_d,
                  bf16* __restrict__ H, float* __restrict__ a_s, float* __restrict__ a_d,
                  int M, const int* __restrict__ ei, int E, int N,
                  int* __restrict__ cnt, int* __restrict__ csr, int ngb) {
  __shared__ bf16 As[64 * 136];
  __shared__ bf16 Bs[64 * 136];
  int b = blockIdx.x;
  if (b < ngb) {
    gemm_body<true>(X, Wt, att_s, att_d, H, a_s, a_d, M, (b >> 2) * 64, b & 3, As, Bs);
  } else {
    int t = (b - ngb) * 256 + threadIdx.x;
    if (t >= E + N) return;
    int src, dst;
    if (t < E) { src = ei[t]; dst = ei[E + t]; }
    else       { src = t - E; dst = t - E; }
    int pos = atomicAdd(&cnt[dst], 1);
    if (pos < CAP) csr[dst * CAP + pos] = src;
  }
}

// ---------------- fused agg(layer k) + gemm(layer k+1) ----------------
// Block owns rows [m0, m0+64). Agg phase: 16 rounds, wave w handles node
// m0 + r*4 + w with the proven wave-per-node inner loop; result rows (bias+ELU,
// bf16) go straight into the As LDS tile (no global round-trip). Gemm phase:
// loop hd=0..3 staging only Bs; As already resident. agg scratch aliases Bs.

__global__ void __launch_bounds__(256, 2)
fused_ag_kernel(const bf16* __restrict__ Hin, const float* __restrict__ as_in,
                const float* __restrict__ ad_in, const int* __restrict__ cnt,
                const int* __restrict__ csr, const float* __restrict__ bias,
                const bf16* __restrict__ Wtn, const float* __restrict__ att_s,
                const float* __restrict__ att_d, bf16* __restrict__ Hout,
                float* __restrict__ as_out, float* __restrict__ ad_out, int N) {
  const int LDKF = 264;  // full 256-k rows + 8 pad (byte stride 528 ≡ 2-way free)
  const int LDK = 136;
  __shared__ bf16 As[64 * 264];   // 33792 B
  __shared__ bf16 Bs[64 * 136];   // 17408 B (agg scratch aliases: 2048+8192 B)
  int tid = threadIdx.x;
  int wave = tid >> 6, lane = tid & 63;
  int m0 = blockIdx.x * 64;

  // ---- agg phase ----
  int*   wIdx = (int*)((char*)Bs + (size_t)wave * 512);            // 128 ints/wave
  float* wP   = (float*)((char*)Bs + 2048 + (size_t)wave * 2048);  // 512 f32/wave
  int sel = lane >> 5, l32 = lane & 31;
  int c8 = l32 * 8, head = l32 >> 3;
  const unsigned short* Hs = (const unsigned short*)Hin;

  for (int r = 0; r < 16; r++) {
    int n = m0 + r * 4 + wave;
    int deg = 0, degp = 0;
    if (n < N) {
      deg = min(cnt[n], CAP);
      degp = (deg + 7) & ~7;
      float4 ad4 = *(const float4*)&ad_in[n * 4];
#pragma unroll
      for (int base = 0; base < 2; base++) {
        int jj = base * 64 + lane;
        if (jj < deg) {
          int src = csr[n * CAP + jj];
          wIdx[jj] = src;
          float4 as4 = *(const float4*)&as_in[src * 4];
          float4 e;
          e.x = as4.x + ad4.x; e.x = (e.x > 0.f) ? e.x : 0.2f * e.x;
          e.y = as4.y + ad4.y; e.y = (e.y > 0.f) ? e.y : 0.2f * e.y;
          e.z = as4.z + ad4.z; e.z = (e.z > 0.f) ? e.z : 0.2f * e.z;
          e.w = as4.w + ad4.w; e.w = (e.w > 0.f) ? e.w : 0.2f * e.w;
          float4 pv;
          pv.x = __expf(e.x); pv.y = __expf(e.y);
          pv.z = __expf(e.z); pv.w = __expf(e.w);
          *(float4*)&wP[jj * 4] = pv;
        }
      }
      int pad = degp - deg;  // 0..7
      if (lane < pad) {
        wIdx[deg + lane] = 0;
        *(float4*)&wP[(deg + lane) * 4] = make_float4(0.f, 0.f, 0.f, 0.f);
      }
    }
    __syncthreads();
    if (n < N) {
      float acc[8] = {0.f, 0.f, 0.f, 0.f, 0.f, 0.f, 0.f, 0.f};
      float s = 0.f;
      int npairp = degp >> 1;  // multiple of 4
      for (int it = 0; it < npairp; it += 4) {
        int jv[4]; int sv[4]; float pv[4]; u16x8 hv[4];
#pragma unroll
        for (int u = 0; u < 4; u++) jv[u] = 2 * (it + u) + sel;
#pragma unroll
        for (int u = 0; u < 4; u++) sv[u] = wIdx[jv[u]];
#pragma unroll
        for (int u = 0; u < 4; u++) pv[u] = wP[jv[u] * 4 + head];
#pragma unroll
        for (int u = 0; u < 4; u++) hv[u] = *(const u16x8*)(Hs + sv[u] * 256 + c8);
#pragma unroll
        for (int u = 0; u < 4; u++) {
          s += pv[u];
#pragma unroll
          for (int k = 0; k < 8; k++) acc[k] += pv[u] * bits2f(hv[u][k]);
        }
      }
      s += __shfl_xor(s, 32, 64);
#pragma unroll
      for (int k = 0; k < 8; k++) acc[k] += __shfl_xor(acc[k], 32, 64);
      if (sel == 0) {
        float inv = 1.f / (s + 1e-16f);
        float4 b0 = *(const float4*)&bias[c8];
        float4 b1 = *(const float4*)&bias[c8 + 4];
        float v[8];
        v[0] = acc[0] * inv + b0.x; v[1] = acc[1] * inv + b0.y;
        v[2] = acc[2] * inv + b0.z; v[3] = acc[3] * inv + b0.w;
        v[4] = acc[4] * inv + b1.x; v[5] = acc[5] * inv + b1.y;
        v[6] = acc[6] * inv + b1.z; v[7] = acc[7] * inv + b1.w;
#pragma unroll
        for (int k = 0; k < 8; k++) v[k] = (v[k] > 0.f) ? v[k] : expm1f(v[k]);
        union { bf16 h[8]; u16x8 u; } pk;
#pragma unroll
        for (int k = 0; k < 8; k++) pk.h[k] = __float2bfloat16(v[k]);
        *(u16x8*)&As[(r * 4 + wave) * LDKF + c8] = pk.u;
      }
    } else if (sel == 0) {
      u16x8 z = {0, 0, 0, 0, 0, 0, 0, 0};
      *(u16x8*)&As[(r * 4 + wave) * LDKF + c8] = z;
    }
    __syncthreads();  // wIdx/wP rounds stay lockstep; As row visible later
  }

  // ---- gemm phase (As resident; Bs region now free) ----
  int quad = lane >> 4, l16 = lane & 15;
  int srow = tid >> 2;
  int koff = (tid & 3) * 32;

  for (int hd = 0; hd < 4; hd++) {
    int n0 = hd * 64;
    f32x4 acc[4] = {{0.f, 0.f, 0.f, 0.f}, {0.f, 0.f, 0.f, 0.f},
                    {0.f, 0.f, 0.f, 0.f}, {0.f, 0.f, 0.f, 0.f}};
    for (int ks = 0; ks < 256; ks += 128) {
#pragma unroll
      for (int c = 0; c < 4; c++) {
        int ko = koff + c * 8;
        *(uint4*)&Bs[srow * LDK + ko] = *(const uint4*)&Wtn[(n0 + srow) * 256 + ks + ko];
      }
      __syncthreads();
#pragma unroll
      for (int kk = 0; kk < 4; kk++) {
        bf16x8v af = *(const bf16x8v*)&As[(wave * 16 + l16) * LDKF + ks + kk * 32 + quad * 8];
#pragma unroll
        for (int t = 0; t < 4; t++) {
          bf16x8v bfr = *(const bf16x8v*)&Bs[(t * 16 + l16) * LDK + kk * 32 + quad * 8];
          acc[t] = __builtin_amdgcn_mfma_f32_16x16x32_bf16(af, bfr, acc[t], 0, 0, 0);
        }
      }
      __syncthreads();
    }
    // epilogue for head hd
    float ps[4] = {0.f, 0.f, 0.f, 0.f}, pd[4] = {0.f, 0.f, 0.f, 0.f};
#pragma unroll
    for (int t = 0; t < 4; t++) {
      float sa = att_s[hd * 64 + t * 16 + l16];
      float da = att_d[hd * 64 + t * 16 + l16];
#pragma unroll
      for (int j = 0; j < 4; j++) {
        int gm = m0 + wave * 16 + quad * 4 + j;
        float v = acc[t][j];
        if (gm < N) Hout[gm * 256 + n0 + t * 16 + l16] = __float2bfloat16(v);
        ps[j] += v * sa;
        pd[j] += v * da;
      }
    }
#pragma unroll
    for (int j = 0; j < 4; j++) {
#pragma unroll
      for (int s = 1; s < 16; s <<= 1) {
        ps[j] += __shfl_xor(ps[j], s, 64);
        pd[j] += __shfl_xor(pd[j], s, 64);
      }
      int gm = m0 + wave * 16 + quad * 4 + j;
      if (l16 == 0 && gm < N) {
        as_out[gm * 4 + hd] = ps[j];
        ad_out[gm * 4 + hd] = pd[j];
      }
    }
  }
}

// ---------------- standalone final agg (wave per node) ----------------

__global__ void __launch_bounds__(256, 8)
agg_final_kernel(const bf16* __restrict__ H, const float* __restrict__ a_s,
                 const float* __restrict__ a_d, const int* __restrict__ cnt,
                 const int* __restrict__ csr, const float* __restrict__ bias,
                 float* __restrict__ OutF, int N) {
  __shared__ int   wIdxS[4][128];
  __shared__ float wPS[4][512];
  int tid = threadIdx.x;
  int wave = tid >> 6, lane = tid & 63;
  int n = blockIdx.x * 4 + wave;
  int* wIdx = wIdxS[wave];
  float* wP = wPS[wave];

  int deg = 0, degp = 0;
  if (n < N) {
    deg = min(cnt[n], CAP);
    degp = (deg + 7) & ~7;
    float4 ad4 = *(const float4*)&a_d[n * 4];
#pragma unroll
    for (int base = 0; base < 2; base++) {
      int jj = base * 64 + lane;
      if (jj < deg) {
        int src = csr[n * CAP + jj];
        wIdx[jj] = src;
        float4 as4 = *(const float4*)&a_s[src * 4];
        float4 e;
        e.x = as4.x + ad4.x; e.x = (e.x > 0.f) ? e.x : 0.2f * e.x;
        e.y = as4.y + ad4.y; e.y = (e.y > 0.f) ? e.y : 0.2f * e.y;
        e.z = as4.z + ad4.z; e.z = (e.z > 0.f) ? e.z : 0.2f * e.z;
        e.w = as4.w + ad4.w; e.w = (e.w > 0.f) ? e.w : 0.2f * e.w;
        float4 pv;
        pv.x = __expf(e.x); pv.y = __expf(e.y);
        pv.z = __expf(e.z); pv.w = __expf(e.w);
        *(float4*)&wP[jj * 4] = pv;
      }
    }
    int pad = degp - deg;
    if (lane < pad) {
      wIdx[deg + lane] = 0;
      *(float4*)&wP[(deg + lane) * 4] = make_float4(0.f, 0.f, 0.f, 0.f);
    }
  }
  __syncthreads();
  if (n >= N) return;

  int sel = lane >> 5;
  int l32 = lane & 31;
  int c8 = l32 * 8;
  int head = l32 >> 3;
  const unsigned short* Hs = (const unsigned short*)H;

  float acc[8] = {0.f, 0.f, 0.f, 0.f, 0.f, 0.f, 0.f, 0.f};
  float s = 0.f;
  int npairp = degp >> 1;

  for (int it = 0; it < npairp; it += 4) {
    int jv[4]; int sv[4]; float pv[4]; u16x8 hv[4];
#pragma unroll
    for (int u = 0; u < 4; u++) jv[u] = 2 * (it + u) + sel;
#pragma unroll
    for (int u = 0; u < 4; u++) sv[u] = wIdx[jv[u]];
#pragma unroll
    for (int u = 0; u < 4; u++) pv[u] = wP[jv[u] * 4 + head];
#pragma unroll
    for (int u = 0; u < 4; u++) hv[u] = *(const u16x8*)(Hs + sv[u] * 256 + c8);
#pragma unroll
    for (int u = 0; u < 4; u++) {
      s += pv[u];
#pragma unroll
      for (int k = 0; k < 8; k++) acc[k] += pv[u] * bits2f(hv[u][k]);
    }
  }

  s += __shfl_xor(s, 32, 64);
#pragma unroll
  for (int k = 0; k < 8; k++) acc[k] += __shfl_xor(acc[k], 32, 64);

  if (sel == 0) {
    float inv = 1.f / (s + 1e-16f);
    float4 b0 = *(const float4*)&bias[c8];
    float4 b1 = *(const float4*)&bias[c8 + 4];
    float v[8];
    v[0] = acc[0] * inv + b0.x; v[1] = acc[1] * inv + b0.y;
    v[2] = acc[2] * inv + b0.z; v[3] = acc[3] * inv + b0.w;
    v[4] = acc[4] * inv + b1.x; v[5] = acc[5] * inv + b1.y;
    v[6] = acc[6] * inv + b1.z; v[7] = acc[7] * inv + b1.w;
#pragma unroll
    for (int k = 0; k < 8; k++) v[k] = (v[k] > 0.f) ? v[k] : expm1f(v[k]);
    *(float4*)&OutF[n * 256 + c8]     = make_float4(v[0], v[1], v[2], v[3]);
    *(float4*)&OutF[n * 256 + c8 + 4] = make_float4(v[4], v[5], v[6], v[7]);
  }
}

// ---------------- launch ----------------

extern "C" void kernel_launch(void* const* d_in, const int* in_sizes, int n_in,
                              void* d_out, int out_size, void* d_ws, size_t ws_size,
                              hipStream_t stream) {
  const int N = in_sizes[0] / 256;   // 10000
  const int E = in_sizes[1] / 2;     // 320000

  const float* x  = (const float*)d_in[0];
  const int*   ei = (const int*)d_in[1];
  const float* Wl[3]  = {(const float*)d_in[2], (const float*)d_in[6], (const float*)d_in[10]};
  const float* asl[3] = {(const float*)d_in[3], (const float*)d_in[7], (const float*)d_in[11]};
  const float* adl[3] = {(const float*)d_in[4], (const float*)d_in[8], (const float*)d_in[12]};
  const float* bl[3]  = {(const float*)d_in[5], (const float*)d_in[9], (const float*)d_in[13]};
  float* out = (float*)d_out;

  char* p = (char*)d_ws;
  auto carve = [&](size_t bytes) {
    char* r = p;
    p += (bytes + 255) & ~size_t(255);
    return r;
  };
  int*   cnt   = (int*)carve(sizeof(int) * N);
  int*   csr   = (int*)carve(sizeof(int) * N * CAP);
  float* a_s   = (float*)carve(sizeof(float) * N * 4);
  float* a_d   = (float*)carve(sizeof(float) * N * 4);
  float* a_s2  = (float*)carve(sizeof(float) * N * 4);
  float* a_d2  = (float*)carve(sizeof(float) * N * 4);
  bf16*  Wt    = (bf16*)carve(sizeof(bf16) * 3 * 65536);
  bf16*  h_buf = (bf16*)carve(sizeof(bf16) * N * 256);
  bf16*  h2buf = (bf16*)carve(sizeof(bf16) * N * 256);
  (void)ws_size; (void)n_in; (void)out_size;

  const int zb = (N + 255) / 256;          // 40 zero blocks
  const int eb = (E + N + 255) / 256;      // 1290 fill blocks
  const int ngb = ((N + 63) / 64) * 4;     // 628 gemm blocks
  const int fb = (N + 63) / 64;            // 157 fused blocks
  const int ab = (N + 3) / 4;              // 2500 final-agg blocks

  // D1: weight transpose + cnt zero
  wt_zero_kernel<<<768 + zb, 256, 0, stream>>>(Wl[0], Wl[1], Wl[2], Wt, cnt, N);
  // D2: layer-1 GEMM + CSR fill (disjoint block ranges)
  gemm1_fill_kernel<<<ngb + eb, 256, 0, stream>>>(x, Wt, asl[0], adl[0], h_buf,
                                                  a_s, a_d, N, ei, E, N, cnt, csr, ngb);
  // D3: agg layer1 (from h_buf, dots a_s/a_d) fused with gemm layer2 -> h2buf, a_s2/a_d2
  fused_ag_kernel<<<fb, 256, 0, stream>>>(h_buf, a_s, a_d, cnt, csr, bl[0],
                                          Wt + 65536, asl[1], adl[1],
                                          h2buf, a_s2, a_d2, N);
  // D4: agg layer2 (from h2buf, dots a_s2/a_d2) fused with gemm layer3 -> h_buf, a_s/a_d
  fused_ag_kernel<<<fb, 256, 0, stream>>>(h2buf, a_s2, a_d2, cnt, csr, bl[1],
                                          Wt + 131072, asl[2], adl[2],
                                          h_buf, a_s, a_d, N);
  // D5: final agg layer3 -> fp32 out
  agg_final_kernel<<<ab, 256, 0, stream>>>(h_buf, a_s, a_d, cnt, csr, bl[2], out, N);
}

// Round 5
// 189.017 us; speedup vs baseline: 3.1834x; 1.5273x over previous
//
#include <hip/hip_runtime.h>
#include <hip/hip_bf16.h>

typedef __hip_bfloat16 bf16;
typedef __bf16 bf16x8v __attribute__((ext_vector_type(8)));
typedef float f32x4 __attribute__((ext_vector_type(4)));
typedef unsigned short u16x8 __attribute__((ext_vector_type(8)));

#define CAP 128  // fixed per-node CSR capacity (mean deg 33; P(deg>128) ~ 0)

__device__ __forceinline__ float bits2f(unsigned short u) {
  union { unsigned int i; float f; } c;
  c.i = ((unsigned int)u) << 16;
  return c.f;
}

// ---------------- shared MFMA GEMM body (r10-verified, BK=128) ----------------
// H[64 rows @ m0, 64 cols @ head hd] = X @ W^T + fused attention dots.
// WF32: stage Bs straight from fp32 W[k][n] (transposed read, coalesced along n).

template <bool FP32IN, bool WF32>
__device__ __forceinline__ void gemm_body(const void* __restrict__ Xv,
                                          const void* __restrict__ Wv,
                                          const float* __restrict__ att_s,
                                          const float* __restrict__ att_d,
                                          bf16* __restrict__ H, float* __restrict__ a_s,
                                          float* __restrict__ a_d, int M, int m0, int hd,
                                          bf16* As, bf16* Bs) {
  const int LDK = 136;
  int tid = threadIdx.x;
  int wave = tid >> 6, lane = tid & 63;
  int quad = lane >> 4, l16 = lane & 15;
  int n0 = hd * 64;
  int srow = tid >> 2;
  int koff = (tid & 3) * 32;

  const float* Xf = (const float*)Xv;
  const bf16*  Xb = (const bf16*)Xv;
  const float* Wf = (const float*)Wv;
  const bf16*  Wb = (const bf16*)Wv;

  f32x4 acc[4] = {{0.f, 0.f, 0.f, 0.f}, {0.f, 0.f, 0.f, 0.f},
                  {0.f, 0.f, 0.f, 0.f}, {0.f, 0.f, 0.f, 0.f}};

  for (int ks = 0; ks < 256; ks += 128) {
    int gm = m0 + srow;
#pragma unroll
    for (int c = 0; c < 4; c++) {
      int ko = koff + c * 8;
      uint4 v;
      if (FP32IN) {
        float4 u0 = make_float4(0.f, 0.f, 0.f, 0.f), u1 = u0;
        if (gm < M) {
          u0 = *(const float4*)&Xf[gm * 256 + ks + ko];
          u1 = *(const float4*)&Xf[gm * 256 + ks + ko + 4];
        }
        union { bf16 h[8]; uint4 u; } pk;
        pk.h[0] = __float2bfloat16(u0.x); pk.h[1] = __float2bfloat16(u0.y);
        pk.h[2] = __float2bfloat16(u0.z); pk.h[3] = __float2bfloat16(u0.w);
        pk.h[4] = __float2bfloat16(u1.x); pk.h[5] = __float2bfloat16(u1.y);
        pk.h[6] = __float2bfloat16(u1.z); pk.h[7] = __float2bfloat16(u1.w);
        v = pk.u;
      } else {
        v = (gm < M) ? *(const uint4*)&Xb[gm * 256 + ks + ko]
                     : make_uint4(0u, 0u, 0u, 0u);
      }
      *(uint4*)&As[srow * LDK + ko] = v;
    }
    if (WF32) {
      // Bs[n][k-ks] = bf16(W[k][n0+n]); lanes span n (coalesced 256B reads)
      int tn = tid & 63, kq = tid >> 6;
#pragma unroll
      for (int i = 0; i < 32; i++) {
        int kk2 = kq * 32 + i;
        Bs[tn * LDK + kk2] = __float2bfloat16(Wf[(size_t)(ks + kk2) * 256 + n0 + tn]);
      }
    } else {
#pragma unroll
      for (int c = 0; c < 4; c++) {
        int ko = koff + c * 8;
        *(uint4*)&Bs[srow * LDK + ko] = *(const uint4*)&Wb[(n0 + srow) * 256 + ks + ko];
      }
    }
    __syncthreads();

#pragma unroll
    for (int kk = 0; kk < 4; kk++) {
      bf16x8v af = *(const bf16x8v*)&As[(wave * 16 + l16) * LDK + kk * 32 + quad * 8];
#pragma unroll
      for (int t = 0; t < 4; t++) {
        bf16x8v bfr = *(const bf16x8v*)&Bs[(t * 16 + l16) * LDK + kk * 32 + quad * 8];
        acc[t] = __builtin_amdgcn_mfma_f32_16x16x32_bf16(af, bfr, acc[t], 0, 0, 0);
      }
    }
    __syncthreads();
  }

  float ps[4] = {0.f, 0.f, 0.f, 0.f}, pd[4] = {0.f, 0.f, 0.f, 0.f};
#pragma unroll
  for (int t = 0; t < 4; t++) {
    float sa = att_s[hd * 64 + t * 16 + l16];
    float da = att_d[hd * 64 + t * 16 + l16];
#pragma unroll
    for (int j = 0; j < 4; j++) {
      int gm = m0 + wave * 16 + quad * 4 + j;
      float v = acc[t][j];
      if (gm < M) H[gm * 256 + n0 + t * 16 + l16] = __float2bfloat16(v);
      ps[j] += v * sa;
      pd[j] += v * da;
    }
  }
#pragma unroll
  for (int j = 0; j < 4; j++) {
#pragma unroll
    for (int s = 1; s < 16; s <<= 1) {
      ps[j] += __shfl_xor(ps[j], s, 64);
      pd[j] += __shfl_xor(pd[j], s, 64);
    }
    int gm = m0 + wave * 16 + quad * 4 + j;
    if (l16 == 0 && gm < M) {
      a_s[gm * 4 + hd] = ps[j];
      a_d[gm * 4 + hd] = pd[j];
    }
  }
}

// layers 2/3: plain gemm, 2D grid
__global__ void __launch_bounds__(256, 4)
gemm_mfma_kernel(const bf16* __restrict__ X, const bf16* __restrict__ Wt,
                 const float* __restrict__ att_s, const float* __restrict__ att_d,
                 bf16* __restrict__ H, float* __restrict__ a_s, float* __restrict__ a_d,
                 int M) {
  __shared__ bf16 As[64 * 136];
  __shared__ bf16 Bs[64 * 136];
  gemm_body<false, false>(X, Wt, att_s, att_d, H, a_s, a_d, M, blockIdx.x * 64,
                          blockIdx.y, As, Bs);
}

// layer 1 + CSR fill + W1/W2 transpose, one dispatch (disjoint block ranges):
// [0,ngb): gemm1 (Bs from fp32 W0 directly); [ngb,ngb+eb): edge scatter;
// [ngb+eb, ngb+eb+512): transpose W1/W2 -> Wt[1],Wt[2] for later dispatches.
__global__ void __launch_bounds__(256, 4)
gemm1_fill_kernel(const float* __restrict__ X, const float* __restrict__ W0,
                  const float* __restrict__ att_s, const float* __restrict__ att_d,
                  bf16* __restrict__ H, float* __restrict__ a_s, float* __restrict__ a_d,
                  int M, const int* __restrict__ ei, int E, int N,
                  int* __restrict__ cnt, int* __restrict__ csr, int ngb, int eb,
                  const float* __restrict__ W1, const float* __restrict__ W2,
                  bf16* __restrict__ Wt) {
  __shared__ bf16 As[64 * 136];
  __shared__ bf16 Bs[64 * 136];
  __shared__ float tile[16][17];
  int b = blockIdx.x;
  if (b < ngb) {
    gemm_body<true, true>(X, W0, att_s, att_d, H, a_s, a_d, M, (b >> 2) * 64, b & 3,
                          As, Bs);
  } else if (b < ngb + eb) {
    int t = (b - ngb) * 256 + threadIdx.x;
    if (t >= E + N) return;
    int src, dst;
    if (t < E) { src = ei[t]; dst = ei[E + t]; }
    else       { src = t - E; dst = t - E; }
    int pos = atomicAdd(&cnt[dst], 1);
    if (pos < CAP) csr[dst * CAP + pos] = src;
  } else {
    int b2 = b - ngb - eb;              // 0..511
    int L = 1 + (b2 >> 8), rem = b2 & 255;
    const float* W = (L == 1) ? W1 : W2;
    bf16* T = Wt + (size_t)L * 65536;
    int n0 = (rem & 15) * 16, k0 = (rem >> 4) * 16;
    int tx = threadIdx.x & 15, ty = threadIdx.x >> 4;
    tile[ty][tx] = W[(k0 + ty) * 256 + n0 + tx];
    __syncthreads();
    T[(n0 + ty) * 256 + k0 + tx] = __float2bfloat16(tile[tx][ty]);
  }
}

// ---------------- wave-per-node agg ----------------
// One wave owns one dst node; wIdx/wP are wave-private LDS slices, so no block
// barrier is needed: a wave-local s_waitcnt lgkmcnt(0) orders the phase-1 LDS
// writes before the phase-2 reads (LDS ops retire in-order within a wave).
// Decouples the 4 waves (no straggler coupling on high-degree nodes).

template <bool FINAL>
__global__ void __launch_bounds__(256, 8)
agg_wave_kernel(const bf16* __restrict__ H, const float* __restrict__ a_s,
                const float* __restrict__ a_d, const int* __restrict__ cnt,
                const int* __restrict__ csr, const float* __restrict__ bias,
                bf16* __restrict__ OutB, float* __restrict__ OutF, int N) {
  __shared__ int   wIdxS[4][128];
  __shared__ float wPS[4][512];
  int tid = threadIdx.x;
  int wave = tid >> 6, lane = tid & 63;
  int n = blockIdx.x * 4 + wave;
  int* wIdx = wIdxS[wave];
  float* wP = wPS[wave];
  if (n >= N) return;

  int deg = min(cnt[n], CAP);
  int degp = (deg + 7) & ~7;          // pad to multiple of 8 edges
  {
    float4 ad4 = *(const float4*)&a_d[n * 4];
#pragma unroll
    for (int base = 0; base < 2; base++) {
      int jj = base * 64 + lane;
      if (jj < deg) {
        int src = csr[n * CAP + jj];
        wIdx[jj] = src;
        float4 as4 = *(const float4*)&a_s[src * 4];
        float4 e;
        e.x = as4.x + ad4.x; e.x = (e.x > 0.f) ? e.x : 0.2f * e.x;
        e.y = as4.y + ad4.y; e.y = (e.y > 0.f) ? e.y : 0.2f * e.y;
        e.z = as4.z + ad4.z; e.z = (e.z > 0.f) ? e.z : 0.2f * e.z;
        e.w = as4.w + ad4.w; e.w = (e.w > 0.f) ? e.w : 0.2f * e.w;
        float4 pv;
        pv.x = __expf(e.x); pv.y = __expf(e.y);
        pv.z = __expf(e.z); pv.w = __expf(e.w);
        *(float4*)&wP[jj * 4] = pv;
      }
    }
    int pad = degp - deg;             // 0..7
    if (lane < pad) {
      wIdx[deg + lane] = 0;
      *(float4*)&wP[(deg + lane) * 4] = make_float4(0.f, 0.f, 0.f, 0.f);
    }
  }
  // wave-local fence: LDS writes above visible to all lanes of this wave
  asm volatile("s_waitcnt lgkmcnt(0)" ::: "memory");
  __builtin_amdgcn_sched_barrier(0);

  int sel = lane >> 5;                // 0: even edges, 1: odd edges
  int l32 = lane & 31;
  int c8 = l32 * 8;                   // 8 channels per lane
  int head = l32 >> 3;
  const unsigned short* Hs = (const unsigned short*)H;

  float acc[8] = {0.f, 0.f, 0.f, 0.f, 0.f, 0.f, 0.f, 0.f};
  float s = 0.f;
  int npairp = degp >> 1;             // multiple of 4

  for (int it = 0; it < npairp; it += 4) {
    int jv[4]; int sv[4]; float pv[4]; u16x8 hv[4];
#pragma unroll
    for (int u = 0; u < 4; u++) jv[u] = 2 * (it + u) + sel;
#pragma unroll
    for (int u = 0; u < 4; u++) sv[u] = wIdx[jv[u]];
#pragma unroll
    for (int u = 0; u < 4; u++) pv[u] = wP[jv[u] * 4 + head];
#pragma unroll
    for (int u = 0; u < 4; u++) hv[u] = *(const u16x8*)(Hs + sv[u] * 256 + c8);
#pragma unroll
    for (int u = 0; u < 4; u++) {
      s += pv[u];
#pragma unroll
      for (int k = 0; k < 8; k++) acc[k] += pv[u] * bits2f(hv[u][k]);
    }
  }

  // merge even/odd halves
  s += __shfl_xor(s, 32, 64);
#pragma unroll
  for (int k = 0; k < 8; k++) acc[k] += __shfl_xor(acc[k], 32, 64);

  if (sel == 0) {
    float inv = 1.f / (s + 1e-16f);
    float4 b0 = *(const float4*)&bias[c8];
    float4 b1 = *(const float4*)&bias[c8 + 4];
    float v[8];
    v[0] = acc[0] * inv + b0.x; v[1] = acc[1] * inv + b0.y;
    v[2] = acc[2] * inv + b0.z; v[3] = acc[3] * inv + b0.w;
    v[4] = acc[4] * inv + b1.x; v[5] = acc[5] * inv + b1.y;
    v[6] = acc[6] * inv + b1.z; v[7] = acc[7] * inv + b1.w;
#pragma unroll
    for (int k = 0; k < 8; k++) v[k] = (v[k] > 0.f) ? v[k] : expm1f(v[k]);
    if (FINAL) {
      *(float4*)&OutF[n * 256 + c8]     = make_float4(v[0], v[1], v[2], v[3]);
      *(float4*)&OutF[n * 256 + c8 + 4] = make_float4(v[4], v[5], v[6], v[7]);
    } else {
      union { bf16 h[8]; u16x8 u; } pk;
#pragma unroll
      for (int k = 0; k < 8; k++) pk.h[k] = __float2bfloat16(v[k]);
      *(u16x8*)((unsigned short*)OutB + n * 256 + c8) = pk.u;
    }
  }
}

// ---------------- launch ----------------

extern "C" void kernel_launch(void* const* d_in, const int* in_sizes, int n_in,
                              void* d_out, int out_size, void* d_ws, size_t ws_size,
                              hipStream_t stream) {
  const int N = in_sizes[0] / 256;   // 10000
  const int E = in_sizes[1] / 2;     // 320000

  const float* x  = (const float*)d_in[0];
  const int*   ei = (const int*)d_in[1];
  const float* Wl[3]  = {(const float*)d_in[2], (const float*)d_in[6], (const float*)d_in[10]};
  const float* asl[3] = {(const float*)d_in[3], (const float*)d_in[7], (const float*)d_in[11]};
  const float* adl[3] = {(const float*)d_in[4], (const float*)d_in[8], (const float*)d_in[12]};
  const float* bl[3]  = {(const float*)d_in[5], (const float*)d_in[9], (const float*)d_in[13]};
  float* out = (float*)d_out;

  char* p = (char*)d_ws;
  auto carve = [&](size_t bytes) {
    char* r = p;
    p += (bytes + 255) & ~size_t(255);
    return r;
  };
  int*   cnt   = (int*)carve(sizeof(int) * N);
  int*   csr   = (int*)carve(sizeof(int) * N * CAP);
  float* a_s   = (float*)carve(sizeof(float) * N * 4);
  float* a_d   = (float*)carve(sizeof(float) * N * 4);
  bf16*  Wt    = (bf16*)carve(sizeof(bf16) * 3 * 65536);   // Wt[0] unused now
  bf16*  h_buf = (bf16*)carve(sizeof(bf16) * N * 256);
  bf16*  x_buf = (bf16*)carve(sizeof(bf16) * N * 256);
  (void)ws_size; (void)n_in; (void)out_size;

  const int eb  = (E + N + 255) / 256;     // 1290 fill blocks
  const int ngb = ((N + 63) / 64) * 4;     // 628 gemm blocks
  const int ab  = (N + 3) / 4;             // 2500 agg blocks (wave per node)
  dim3 ggrid((N + 63) / 64, 4);

  // D0: zero the CSR counters (stream memset, graph-capturable)
  hipMemsetAsync(cnt, 0, sizeof(int) * N, stream);
  // D1: layer-1 GEMM (direct fp32 W0) + CSR fill + W1/W2 transpose
  gemm1_fill_kernel<<<ngb + eb + 512, 256, 0, stream>>>(
      x, Wl[0], asl[0], adl[0], h_buf, a_s, a_d, N, ei, E, N, cnt, csr, ngb, eb,
      Wl[1], Wl[2], Wt);
  // D2..D6
  agg_wave_kernel<false><<<ab, 256, 0, stream>>>(h_buf, a_s, a_d, cnt, csr, bl[0],
                                                 x_buf, nullptr, N);
  gemm_mfma_kernel<<<ggrid, 256, 0, stream>>>(x_buf, Wt + 65536, asl[1], adl[1],
                                              h_buf, a_s, a_d, N);
  agg_wave_kernel<false><<<ab, 256, 0, stream>>>(h_buf, a_s, a_d, cnt, csr, bl[1],
                                                 x_buf, nullptr, N);
  gemm_mfma_kernel<<<ggrid, 256, 0, stream>>>(x_buf, Wt + 131072, asl[2], adl[2],
                                              h_buf, a_s, a_d, N);
  agg_wave_kernel<true><<<ab, 256, 0, stream>>>(h_buf, a_s, a_d, cnt, csr, bl[2],
                                                nullptr, out, N);
}